// Round 13
// baseline (386.500 us; speedup 1.0000x reference)
//
#include <hip/hip_runtime.h>

#define N_ENT   100000
#define N_REL   500
#define DD      50
#define LD      52      // fp32 stride for sequentially-read tables (EW1/Ed/e0): 208 B
#define LD2     64      // fp32 stride for RW (L2-resident gather): 256 B
#define LDH     64      // bf16 stride for EW3h: 64 shorts = 128 B = 1 cache line
#define N_EDGES 2000000
#define T_BITS  17
#define T_MASK  0x1FFFF
#define BBITS   9                    // 512 entities per coarse bucket
#define BMASK   511
#define NB      196                  // ceil(N_ENT / 512)
#define CHUNK   4096                 // edges per bucket_scatter block (512 thr)
#define SSH     14                   // log2 staging slots per bucket
#define SSTRIDE (1 << SSH)           // 16384 slots/bucket: mean 10240, sigma~101
#define ENT_BLOCKS   2500            // N_ENT / 40
#define BKT_BLOCKS   489             // ceil(N_EDGES / CHUNK)
#define REL_BLOCKS   100             // N_REL / 5
#define UHALF   50000                // head-split point for accum0/ent1 pipeline
#define ACCB    3125                 // UHALF / 16 heads per 512-thr block
#define E1HB    1250                 // ent blocks per half (UHALF / 40)

typedef float v2f __attribute__((ext_vector_type(2)));

__device__ inline unsigned int pack_bf2(float x, float y) {
    unsigned int xu = __float_as_uint(x);
    unsigned int yu = __float_as_uint(y);
    xu = (xu + 0x7FFFu + ((xu >> 16) & 1u)) >> 16;   // round-to-nearest-even
    yu = (yu + 0x7FFFu + ((yu >> 16) & 1u)) >> 16;
    return xu | (yu << 16);
}
__device__ inline v2f unpk2(unsigned int v) {
    v2f r;
    r.x = __uint_as_float(v << 16);
    r.y = __uint_as_float(v & 0xFFFF0000u);
    return r;
}

// ---------------------------------------------------------------------------
// ent_pre body (best measured): 2x2 tiles, 512 threads, MT=40, simple k-loop.
//   Ya[m][:]  = X@Wa   fp32 stride LD  ; shOut[m] = row.a
//   Ybh[m][:] = X@Wb   bf16 stride LDH ; stOut[m] = row.a (dot from fp32)
//   Yc[m][:]  = X@Wc+bd fp32 stride LD   [NMAT==3 only]
// ---------------------------------------------------------------------------
template<int NMAT>
__device__ void ent_pre_body(float* smemF, int bid,
    const float* __restrict__ X, int ldX,
    const float* __restrict__ Wa,
    const float* __restrict__ Wb,
    const float* __restrict__ Wc,
    const float* __restrict__ bd,
    const float* __restrict__ avec,
    float* __restrict__ Ya,
    unsigned short* __restrict__ Ybh,
    float* __restrict__ Yc,
    float* __restrict__ shOut,
    float* __restrict__ stOut)
{
    constexpr int MT = 40;       // rows per block; N_ENT % MT == 0
    float* sW = smemF;                       // NMAT * DD*DD
    float* sX = sW + NMAT * DD * DD;         // MT*52
    float* sY = sX + MT * 52;                // MT*52
    float* sa = sY + MT * 52;                // DD

    const int tid = threadIdx.x;

    for (int i = tid; i < DD * DD / 4; i += 512) {
        ((float4*)sW)[i] = ((const float4*)Wa)[i];
        ((float4*)(sW + DD * DD))[i] = ((const float4*)Wb)[i];
        if (NMAT == 3) ((float4*)(sW + 2 * DD * DD))[i] = ((const float4*)Wc)[i];
    }
    if (tid < DD) sa[tid] = avec[tid];

    const int m0 = bid * MT;
    const int nX4 = MT * ldX / 4;
    const float4* xsrc = (const float4*)(X + (size_t)m0 * ldX);
    for (int i = tid; i < nX4; i += 512) ((float4*)sX)[i] = xsrc[i];
    __syncthreads();

    const bool active = (tid < 500);
    const int mp = active ? tid / 25 : 0;       // 0..19
    const int jp = active ? tid % 25 : 0;       // 0..24
    const int r0 = 2 * mp, r1 = 2 * mp + 1, j0 = 2 * jp;

    float acc[NMAT][2][2];
    #pragma unroll
    for (int t = 0; t < NMAT; t++)
        #pragma unroll
        for (int i = 0; i < 2; i++)
            #pragma unroll
            for (int c = 0; c < 2; c++) acc[t][i][c] = 0.f;

    if (active) {
        if (NMAT == 3) {
            float b0 = bd[j0], b1 = bd[j0 + 1];
            acc[2][0][0] = b0; acc[2][0][1] = b1;
            acc[2][1][0] = b0; acc[2][1][1] = b1;
        }
        const float* xr0 = &sX[r0 * ldX];
        const float* xr1 = &sX[r1 * ldX];
        for (int k = 0; k < DD; k++) {
            float x0 = xr0[k], x1 = xr1[k];
            #pragma unroll
            for (int t = 0; t < NMAT; t++) {
                float2 w = *(const float2*)&sW[t * DD * DD + k * DD + j0];
                acc[t][0][0] += x0 * w.x; acc[t][0][1] += x0 * w.y;
                acc[t][1][0] += x1 * w.x; acc[t][1][1] += x1 * w.y;
            }
        }
    }

    // zero fp32 pad cols 50,51
    if (tid < MT * 2) sY[(tid >> 1) * 52 + 50 + (tid & 1)] = 0.f;

    // ---- stage 0: Ya (fp32, stride LD) + sh dot ----
    if (active) {
        sY[r0 * 52 + j0]     = acc[0][0][0];
        sY[r0 * 52 + j0 + 1] = acc[0][0][1];
        sY[r1 * 52 + j0]     = acc[0][1][0];
        sY[r1 * 52 + j0 + 1] = acc[0][1][1];
    }
    __syncthreads();
    {
        float4* dst = (float4*)(Ya + (size_t)m0 * LD);
        for (int i = tid; i < MT * LD / 4; i += 512) dst[i] = ((const float4*)sY)[i];
        if (tid < MT) {
            const float* row = &sY[tid * 52];
            float d = 0.f;
            for (int k = 0; k < DD; k++) d += row[k] * sa[k];
            shOut[m0 + tid] = d;
        }
    }
    __syncthreads();

    // ---- stage 1: Ybh (bf16, stride LDH) + st dot (from fp32) ----
    unsigned int* sYhU = (unsigned int*)sX;       // sX dead after compute
    if (active) {
        sY[r0 * 52 + j0]     = acc[1][0][0];
        sY[r0 * 52 + j0 + 1] = acc[1][0][1];
        sY[r1 * 52 + j0]     = acc[1][1][0];
        sY[r1 * 52 + j0 + 1] = acc[1][1][1];
        sYhU[r0 * 32 + jp] = pack_bf2(acc[1][0][0], acc[1][0][1]);
        sYhU[r1 * 32 + jp] = pack_bf2(acc[1][1][0], acc[1][1][1]);
    }
    if (tid < MT * 7) sYhU[(tid / 7) * 32 + 25 + (tid % 7)] = 0u;  // bf16 pads
    __syncthreads();
    {
        float4* dst = (float4*)(Ybh + (size_t)m0 * LDH);
        for (int i = tid; i < MT * LDH * 2 / 16; i += 512) dst[i] = ((const float4*)sYhU)[i];
        if (tid < MT) {
            const float* row = &sY[tid * 52];
            float d = 0.f;
            for (int k = 0; k < DD; k++) d += row[k] * sa[k];
            stOut[m0 + tid] = d;
        }
    }

    // ---- stage 2: Yc (fp32, stride LD)  [NMAT==3] ----
    if (NMAT == 3) {
        __syncthreads();
        if (active) {
            sY[r0 * 52 + j0]     = acc[2][0][0];
            sY[r0 * 52 + j0 + 1] = acc[2][0][1];
            sY[r1 * 52 + j0]     = acc[2][1][0];
            sY[r1 * 52 + j0 + 1] = acc[2][1][1];
        }
        __syncthreads();
        float4* dst = (float4*)(Yc + (size_t)m0 * LD);
        for (int i = tid; i < MT * LD / 4; i += 512) dst[i] = ((const float4*)sY)[i];
    }
}

// standalone wrapper (layer 1), with block-id base for half-range launches
template<int NMAT>
__global__ __launch_bounds__(512) void ent_pre_v6(
    const float* __restrict__ X, int ldX,
    const float* __restrict__ Wa,
    const float* __restrict__ Wb,
    const float* __restrict__ avec,
    float* __restrict__ Ya,
    unsigned short* __restrict__ Ybh,
    float* __restrict__ shOut,
    float* __restrict__ stOut,
    int bid_base)
{
    __shared__ __align__(16) float smemF[NMAT * DD * DD + 40 * 52 * 2 + 64];
    ent_pre_body<NMAT>(smemF, blockIdx.x + bid_base, X, ldX, Wa, Wb,
                       nullptr, nullptr, avec, Ya, Ybh, nullptr, shOut, stOut);
}

// ---------------------------------------------------------------------------
// rel body: rel_out = (relu?) Rin @ Wr (stride ld_rel);
// RW_out = Rin @ Wmid (fp32 stride LD2); sr[m] = RW_out[m][:50].a
// 5 rows per block, uses first 250 threads (safe in 256/512-thr blocks).
// ---------------------------------------------------------------------------
__device__ void rel_body(float* smemF, int bid,
    const float* __restrict__ Rin, int ld_in,
    const float* __restrict__ Wr,
    const float* __restrict__ Wmid,
    const float* __restrict__ avec,
    int do_relu,
    float* __restrict__ rel_out, int ld_rel,
    float* __restrict__ RW_out,
    float* __restrict__ sr)
{
    float* sWr  = smemF;           // DD*DD
    float* sWm  = sWr + DD * DD;   // DD*DD
    float* sRed = sWm + DD * DD;   // 256

    for (int i = threadIdx.x; i < DD * DD; i += blockDim.x) {
        sWr[i] = Wr[i];
        sWm[i] = Wmid[i];
    }
    __syncthreads();
    const int tid = threadIdx.x;
    const bool act = (tid < 250);
    const int m = bid * 5 + tid / 50;
    const int j = tid % 50;
    float am = 0.f;
    if (act) {
        const float* x = Rin + (size_t)m * ld_in;
        float ar = 0.f;
        for (int k = 0; k < DD; k++) {
            float xv = x[k];
            ar += xv * sWr[k * DD + j];
            am += xv * sWm[k * DD + j];
        }
        if (do_relu) ar = fmaxf(ar, 0.f);
        rel_out[(size_t)m * ld_rel + j] = ar;
        RW_out[(size_t)m * LD2 + j] = am;
        if (j < LD2 - DD) RW_out[(size_t)m * LD2 + DD + j] = 0.f;
    }
    if (tid < 256) sRed[tid] = act ? am * avec[j] : 0.f;
    __syncthreads();
    if (tid < 5) {
        float d = 0.f;
        const float* p = &sRed[tid * 50];
        for (int k = 0; k < 50; k++) d += p[k];
        sr[bid * 5 + tid] = d;
    }
}

// ---------------------------------------------------------------------------
// CSR build (fixed-stride staging: bucket b's region = [b<<SSH, +ccur[b])).
// ---------------------------------------------------------------------------
__device__ void bucket_body(float* smemF, int bid,
    const int* __restrict__ h,
    const int* __restrict__ r,
    const int* __restrict__ t,
    int* __restrict__ ccur,
    unsigned int* __restrict__ stagedP,
    unsigned short* __restrict__ stagedH, int nE)
{
    int* sHist = (int*)smemF;                       // NB
    int* sScan = sHist + NB;                        // 512
    int* sBase = sScan + 512;                       // NB
    int* sCur  = sBase + NB;                        // NB
    int* sGb   = sCur + NB;                         // NB
    unsigned int*   sPay = (unsigned int*)(sGb + NB);       // CHUNK
    unsigned short* sLoc = (unsigned short*)(sPay + CHUNK); // CHUNK shorts
    unsigned char*  sBkt = (unsigned char*)(sLoc + CHUNK);  // CHUNK bytes

    const int tid = threadIdx.x;
    const int e0 = bid * CHUNK;
    const int n = min(CHUNK, nE - e0);

    for (int i = tid; i < NB; i += 512) sHist[i] = 0;
    __syncthreads();

    #pragma unroll
    for (int k = 0; k < CHUNK / 512; k++) {
        int e = e0 + k * 512 + tid;
        if (e < nE) atomicAdd(&sHist[h[e] >> BBITS], 1);
    }
    __syncthreads();

    int v = (tid < NB) ? sHist[tid] : 0;
    sScan[tid] = v;
    __syncthreads();
    for (int off = 1; off < 512; off <<= 1) {
        int x = (tid >= off) ? sScan[tid - off] : 0;
        __syncthreads();
        sScan[tid] += x;
        __syncthreads();
    }
    if (tid < NB) {
        int excl = sScan[tid] - v;
        sBase[tid] = excl;
        sCur[tid] = excl;
    }
    __syncthreads();

    #pragma unroll
    for (int k = 0; k < CHUNK / 512; k++) {
        int e = e0 + k * 512 + tid;
        if (e < nE) {
            int hv = h[e];
            int b = hv >> BBITS;
            int pos = atomicAdd(&sCur[b], 1);
            sPay[pos] = ((unsigned int)r[e] << T_BITS) | (unsigned int)t[e];
            sLoc[pos] = (unsigned short)(hv & BMASK);
            sBkt[pos] = (unsigned char)b;
        }
    }
    __syncthreads();

    // claim [base, base+cnt) inside bucket tid's fixed region
    if (tid < NB) {
        int cnt = sHist[tid];
        sGb[tid] = (tid << SSH) + (cnt ? atomicAdd(&ccur[tid], cnt) : 0);
    }
    __syncthreads();

    for (int i = tid; i < n; i += 512) {
        int b = sBkt[i];
        int g = sGb[b] + (i - sBase[b]);
        stagedP[g] = sPay[i];
        stagedH[g] = sLoc[i];
    }
}

// merged D1: bucket (0..488) || ent_pre0 (489..2988) || rel_pre0 (2989..3088)
__global__ __launch_bounds__(512) void bke_kernel(
    const int* __restrict__ h,
    const int* __restrict__ r,
    const int* __restrict__ t,
    int* __restrict__ ccur,
    unsigned int* __restrict__ stagedP,
    unsigned short* __restrict__ stagedH, int nE,
    // ent layer-0
    const float* __restrict__ E,
    const float* __restrict__ W0,
    const float* __restrict__ Wd,
    const float* __restrict__ bd,
    const float* __restrict__ a0,
    float* __restrict__ EW1,
    unsigned short* __restrict__ EW3h,
    float* __restrict__ Ed,
    float* __restrict__ sh,
    float* __restrict__ st,
    // rel layer-0
    const float* __restrict__ R,
    const float* __restrict__ Wr0,
    const float* __restrict__ Wmid0,
    float* __restrict__ rel0,
    float* __restrict__ RW,
    float* __restrict__ sr)
{
    __shared__ __align__(16) float smemF[3 * DD * DD + 40 * 52 * 2 + 64];
    if (blockIdx.x < BKT_BLOCKS) {
        bucket_body(smemF, blockIdx.x, h, r, t, ccur, stagedP, stagedH, nE);
    } else if (blockIdx.x < BKT_BLOCKS + ENT_BLOCKS) {
        ent_pre_body<3>(smemF, blockIdx.x - BKT_BLOCKS, E, DD,
                        W0, W0 + 2 * DD * DD, Wd, bd, a0,
                        EW1, EW3h, Ed, sh, st);
    } else {
        rel_body(smemF, blockIdx.x - BKT_BLOCKS - ENT_BLOCKS, R, DD,
                 Wr0, Wmid0, a0, 1, rel0, LD, RW, sr);
    }
}

// S2 body: one block per bucket, 512 threads. Window = fixed-stride region.
__device__ void final_scatter_body(float* smemF, int b,
    const unsigned int* __restrict__ stagedP,
    const unsigned short* __restrict__ stagedH,
    const int* __restrict__ ccnt,
    int* __restrict__ counts,
    int* __restrict__ s0,
    unsigned int* __restrict__ rtp)
{
    int* sCnt  = (int*)smemF;        // 512
    int* sScan = sCnt + 512;         // 512
    int* sOff  = sScan + 512;        // 512

    const int i0 = b << SSH;
    const int i1 = i0 + ccnt[b];
    const int tid = threadIdx.x;     // 0..511

    sCnt[tid] = 0;
    __syncthreads();

    for (int i = i0 + tid; i < i1; i += 512)
        atomicAdd(&sCnt[stagedH[i]], 1);
    __syncthreads();

    const int v = sCnt[tid];
    sScan[tid] = v;
    __syncthreads();
    for (int off = 1; off < 512; off <<= 1) {
        int x = (tid >= off) ? sScan[tid - off] : 0;
        __syncthreads();
        sScan[tid] += x;
        __syncthreads();
    }
    const int excl = sScan[tid] - v;
    sOff[tid] = excl;

    const int u = (b << BBITS) + tid;
    if (u < N_ENT) {
        counts[u] = v;
        s0[u] = i0 + excl;
    }
    __syncthreads();   // sOff fully written before use as cursors

    for (int i = i0 + tid; i < i1; i += 512) {
        unsigned int p = stagedP[i];
        int loc = stagedH[i];
        int pos = i0 + atomicAdd(&sOff[loc], 1);
        rtp[pos] = p;
    }
}

// merged D2: final_scatter (0..195) || rel_pre layer 1 (196..295)
__global__ __launch_bounds__(512) void fs_rel1_kernel(
    const unsigned int* __restrict__ stagedP,
    const unsigned short* __restrict__ stagedH,
    const int* __restrict__ ccnt,
    int* __restrict__ counts,
    int* __restrict__ s0,
    unsigned int* __restrict__ rtp,
    const float* __restrict__ rel0,
    const float* __restrict__ Wr1,
    const float* __restrict__ Wmid1,
    const float* __restrict__ a1,
    float* __restrict__ out_rel,
    float* __restrict__ RW1,
    float* __restrict__ sr1)
{
    __shared__ __align__(16) float smemF[2 * DD * DD + 256 + 16];
    if (blockIdx.x < NB) {
        final_scatter_body(smemF, blockIdx.x, stagedP, stagedH, ccnt,
                           counts, s0, rtp);
    } else {
        rel_body(smemF, blockIdx.x - NB, rel0, LD, Wr1, Wmid1, a1, 0,
                 out_rel, DD, RW1, sr1);
    }
}

// ---------------------------------------------------------------------------
// Fused score + accumulate body (R8-best): one head per 32-lane half, packed
// dual-fp32 math, 3-deep software pipeline, no block-wide coupling.
// ---------------------------------------------------------------------------
__device__ void accum_body(int u,
    const int* __restrict__ s0v,
    const int* __restrict__ counts,
    const unsigned int* __restrict__ rtp,
    const float* __restrict__ sh,
    const float* __restrict__ sr,
    const float* __restrict__ st,
    const float* __restrict__ EW1,
    const float* __restrict__ RW,
    const unsigned short* __restrict__ EW3h,
    const float* __restrict__ base,
    float* __restrict__ outp, int full_ld)
{
    const int lane  = threadIdx.x & 63;
    const int half  = lane >> 5;
    const int hlane = lane & 31;
    const int eg = hlane >> 3;         // 0..3 edge group
    const int q  = hlane & 7;          // 0..7 col group
    const int sbase = half << 5;       // shuffle base of this half
    const unsigned qh = (unsigned)q << 4;    // byte offset into EW3h row
    const unsigned qr = (unsigned)q << 5;    // byte offset into RW row

    const int b = s0v[u];
    const int c = counts[u];
    const float shu = sh[u];

    const char* __restrict__ pH = (const char*)EW3h;
    const char* __restrict__ pR = (const char*)RW;
    const char* __restrict__ pS = (const char*)sr;
    const char* __restrict__ pT = (const char*)st;

    v2f acc2[4];
    #pragma unroll
    for (int k = 0; k < 4; k++) { acc2[k].x = 0.f; acc2[k].y = 0.f; }
    float asum = 0.f;

    for (int i0 = 0; i0 < c; i0 += 32) {
        const int cb = min(32, c - i0);            // edges in this batch
        // ---- score phase: hlane scores edge i0+hlane of its head ----
        const int e = i0 + hlane;
        const unsigned w = rtp[b + min(e, c - 1)];
        float ex = 0.f;
        if (e < c) {
            float srv = *(const float*)(pS + ((w >> T_BITS) << 2));
            float stv = *(const float*)(pT + ((w & T_MASK) << 2));
            float sc = shu + srv + stv;
            sc = sc >= 0.f ? sc : 0.2f * sc;
            ex = __expf(sc);
        }
        asum += ex;

        const int nst = (cb + 3) >> 2;             // 4 edges per step per head

#define LOADSTEP(S, TH, VA, VB, EX) {                                   \
        const int _src = sbase + min((S) * 4 + eg, cb - 1);             \
        const unsigned _wv = (unsigned)__shfl((int)w, _src);            \
        EX = __shfl(ex, _src);                                          \
        const unsigned _oH = ((_wv & T_MASK) << 7) | qh;                \
        const unsigned _oR = ((_wv >> T_BITS) << 8) | qr;               \
        TH = *(const uint4*)(pH + _oH);                                 \
        VA = *(const float4*)(pR + _oR);                                \
        VB = *(const float4*)(pR + _oR + 16); }

        uint4 th0, th1; float4 va0, vb0, va1, vb1; float ex0, ex1;
        LOADSTEP(0, th0, va0, vb0, ex0)
        LOADSTEP(1, th1, va1, vb1, ex1)

        for (int s = 0; s < nst; s++) {
            uint4 thn; float4 van, vbn; float exn;
            LOADSTEP(s + 2, thn, van, vbn, exn)    // prefetch 2 steps ahead

            const float exv = (s * 4 + eg < cb) ? ex0 : 0.f;
            v2f ex2; ex2.x = exv; ex2.y = exv;
            v2f p01; p01.x = va0.x; p01.y = va0.y;
            v2f p23; p23.x = va0.z; p23.y = va0.w;
            v2f p45; p45.x = vb0.x; p45.y = vb0.y;
            v2f p67; p67.x = vb0.z; p67.y = vb0.w;
            acc2[0] += ex2 * (p01 + unpk2(th0.x));   // pk_add + pk_fma
            acc2[1] += ex2 * (p23 + unpk2(th0.y));
            acc2[2] += ex2 * (p45 + unpk2(th0.z));
            acc2[3] += ex2 * (p67 + unpk2(th0.w));

            th0 = th1; va0 = va1; vb0 = vb1; ex0 = ex1;
            th1 = thn; va1 = van; vb1 = vbn; ex1 = exn;
        }
#undef LOADSTEP
    }

    // epilogue prefetch: issue EW1/base row loads before the fold
    const int ej = 8 * hlane;
    const bool ep = (hlane < 8) && (ej < LD);
    const bool efull = ep && (ej < 48);
    float4 w1a, w1b, ba, bb;
    if (ep) {
        const float* e1 = EW1 + (size_t)u * LD + (efull ? ej : 48);
        w1a = *(const float4*)e1;
        if (efull) w1b = *(const float4*)(e1 + 4);
        if (base) {
            const float* bp = base + (size_t)u * LD + (efull ? ej : 48);
            ba = *(const float4*)bp;
            if (efull) bb = *(const float4*)(bp + 4);
        }
    }

    // fold within each 32-lane half: acc over 4 edge-groups; asum over 32
    float acc[8];
    #pragma unroll
    for (int k = 0; k < 4; k++) { acc[2 * k] = acc2[k].x; acc[2 * k + 1] = acc2[k].y; }
    #pragma unroll
    for (int off = 16; off >= 8; off >>= 1) {
        #pragma unroll
        for (int k = 0; k < 8; k++) acc[k] += __shfl_down(acc[k], off, 32);
        asum += __shfl_down(asum, off, 32);
    }
    asum += __shfl_xor(asum, 4);
    asum += __shfl_xor(asum, 2);
    asum += __shfl_xor(asum, 1);

    if (hlane >= 8) return;            // lanes 0..7 of each half hold cols
    const int j0 = 8 * hlane;
    if (j0 >= LD) return;              // hlane 7 -> cols 56.. out of range

    if (asum > 0.f) {
        float inv = 1.f / asum;
        if (j0 < 48) {
            acc[0] = w1a.x + acc[0] * inv; acc[1] = w1a.y + acc[1] * inv;
            acc[2] = w1a.z + acc[2] * inv; acc[3] = w1a.w + acc[3] * inv;
            acc[4] = w1b.x + acc[4] * inv; acc[5] = w1b.y + acc[5] * inv;
            acc[6] = w1b.z + acc[6] * inv; acc[7] = w1b.w + acc[7] * inv;
        } else {  // j0 == 48: cols 48,49 real; 50,51 pads (zero everywhere)
            acc[0] = w1a.x + acc[0] * inv; acc[1] = w1a.y + acc[1] * inv;
            acc[2] = w1a.z + acc[2] * inv; acc[3] = w1a.w + acc[3] * inv;
        }
    }  // else: empty segment -> 0, matching ref
    if (base) {
        if (j0 < 48) {
            acc[0] += ba.x; acc[1] += ba.y; acc[2] += ba.z; acc[3] += ba.w;
            acc[4] += bb.x; acc[5] += bb.y; acc[6] += bb.z; acc[7] += bb.w;
        } else {
            acc[0] += ba.x; acc[1] += ba.y; acc[2] += ba.z; acc[3] += ba.w;
        }
    }
    if (full_ld) {                      // stride LD=52, 16B-aligned
        if (j0 < 48) {
            *(float4*)(outp + (size_t)u * LD + j0) =
                make_float4(acc[0], acc[1], acc[2], acc[3]);
            *(float4*)(outp + (size_t)u * LD + j0 + 4) =
                make_float4(acc[4], acc[5], acc[6], acc[7]);
        } else {                        // cols 48..51 (50,51 are exact zeros)
            *(float4*)(outp + (size_t)u * LD + 48) =
                make_float4(acc[0], acc[1], acc[2], acc[3]);
        }
    } else {                            // stride DD=50, rows only 8B-aligned
        float* row = outp + (size_t)u * DD;
        if (j0 < 48) {
            *(float2*)(row + j0)     = make_float2(acc[0], acc[1]);
            *(float2*)(row + j0 + 2) = make_float2(acc[2], acc[3]);
            *(float2*)(row + j0 + 4) = make_float2(acc[4], acc[5]);
            *(float2*)(row + j0 + 6) = make_float2(acc[6], acc[7]);
        } else {
            *(float2*)(row + 48) = make_float2(acc[0], acc[1]);
        }
    }
}

// standalone accum over head range [ubase, ubase+ucount)
__global__ __launch_bounds__(256) void accum_fused_kernel(
    const int* __restrict__ s0v,
    const int* __restrict__ counts,
    const unsigned int* __restrict__ rtp,
    const float* __restrict__ sh,
    const float* __restrict__ sr,
    const float* __restrict__ st,
    const float* __restrict__ EW1,
    const float* __restrict__ RW,
    const unsigned short* __restrict__ EW3h,
    const float* __restrict__ base,
    float* __restrict__ outp, int full_ld,
    int ubase, int ucount)
{
    const int wid = (blockIdx.x * blockDim.x + threadIdx.x) >> 6;
    if (2 * wid >= ucount) return;
    const int u = ubase + 2 * wid + ((threadIdx.x >> 5) & 1);
    accum_body(u, s0v, counts, rtp, sh, sr, st, EW1, RW, EW3h,
               base, outp, full_ld);
}

// merged D4: accum0 heads [UHALF, N_ENT) (blocks 0..ACCB-1, 16 heads each)
//          || ent_pre layer-1 rows [0, UHALF) (blocks ACCB..ACCB+E1HB-1)
__global__ __launch_bounds__(512) void acc_ent_kernel(
    // accum layer-0 args
    const int* __restrict__ s0v,
    const int* __restrict__ counts,
    const unsigned int* __restrict__ rtp,
    const float* __restrict__ sh,
    const float* __restrict__ sr,
    const float* __restrict__ st,
    const float* __restrict__ EW1,
    const float* __restrict__ RW,
    const unsigned short* __restrict__ EW3h,
    float* __restrict__ e0,
    // ent layer-1 args (separate layer-1 tables)
    const float* __restrict__ W1a,
    const float* __restrict__ W1c,
    const float* __restrict__ a1,
    unsigned short* __restrict__ EW3hb,
    float* __restrict__ sh1,
    float* __restrict__ st1)
{
    __shared__ __align__(16) float smemF[2 * DD * DD + 40 * 52 * 2 + 64];
    if (blockIdx.x < ACCB) {
        const int wid = (blockIdx.x * 512 + threadIdx.x) >> 6;
        const int u = UHALF + 2 * wid + ((threadIdx.x >> 5) & 1);
        accum_body(u, s0v, counts, rtp, sh, sr, st, EW1, RW, EW3h,
                   nullptr, e0, 1);
    } else {
        // ent1 half 1: reads e0 rows [0,UHALF) (done), writes EW1 rows
        // [0,UHALF) (disjoint from accum's reads of rows [UHALF,N_ENT))
        ent_pre_body<2>(smemF, blockIdx.x - ACCB, e0, LD, W1a, W1c,
                        nullptr, nullptr, a1,
                        (float*)EW1, EW3hb, nullptr, sh1, st1);
    }
}

// ---------------------------------------------------------------------------
extern "C" void kernel_launch(void* const* d_in, const int* in_sizes, int n_in,
                              void* d_out, int out_size, void* d_ws, size_t ws_size,
                              hipStream_t stream)
{
    const int*   h   = (const int*)d_in[0];
    const int*   r   = (const int*)d_in[1];
    const int*   t   = (const int*)d_in[2];
    const float* E   = (const float*)d_in[3];
    const float* R   = (const float*)d_in[4];
    const float* W0  = (const float*)d_in[5];
    const float* a0  = (const float*)d_in[6];
    const float* Wr0 = (const float*)d_in[7];
    const float* W1  = (const float*)d_in[8];
    const float* a1  = (const float*)d_in[9];
    const float* Wr1 = (const float*)d_in[10];
    const float* Wd  = (const float*)d_in[11];
    const float* bd  = (const float*)d_in[12];

    float* out_ent = (float*)d_out;                 // [N_ENT, DD] stride DD
    float* out_rel = out_ent + (size_t)N_ENT * DD;  // [N_REL, DD] stride DD

    // workspace layout (base ~90 MB; +13.6 MB for split-tail path)
    float* ws_f  = (float*)d_ws;
    float* EW1   = ws_f;                                   // N_ENT*LD
    float* Ed    = EW1  + (size_t)N_ENT * LD;              // N_ENT*LD
    float* e0    = Ed   + (size_t)N_ENT * LD;              // N_ENT*LD
    unsigned short* EW3h = (unsigned short*)(e0 + (size_t)N_ENT * LD);  // N_ENT*LDH bf16
    float* RW    = (float*)(EW3h + (size_t)N_ENT * LDH);   // N_REL*LD2
    float* RW1   = RW   + (size_t)N_REL * LD2;             // N_REL*LD2
    float* rel0  = RW1  + (size_t)N_REL * LD2;             // N_REL*LD
    float* sh    = rel0 + (size_t)N_REL * LD;              // N_ENT
    float* st    = sh   + N_ENT;                           // N_ENT
    float* sr    = st   + N_ENT;                           // N_REL
    float* sr1   = sr   + N_REL;                           // N_REL
    int* counts  = (int*)(sr1 + N_REL);                    // N_ENT
    int* s0      = counts + N_ENT;                         // N_ENT
    int* ccur    = s0 + N_ENT;                             // NB
    unsigned int* rtp    = (unsigned int*)(ccur + NB);     // NB*SSTRIDE (12.8 MB)
    // split-tail extra buffers (layer-1 tables must not overwrite layer-0
    // while accum0's second half still gathers layer-0 globally):
    unsigned short* EW3hb = (unsigned short*)(rtp + (size_t)NB * SSTRIDE); // N_ENT*LDH
    float* sh1   = (float*)(EW3hb + (size_t)N_ENT * LDH);  // N_ENT
    float* st1   = sh1 + N_ENT;                            // N_ENT
    const size_t needA = (size_t)((char*)(st1 + N_ENT) - (char*)d_ws);
    const bool split = (ws_size >= needA);
    if (!split) {                      // fallback: serial tail, in-place tables
        EW3hb = EW3h;
        sh1 = sh;
        st1 = st;
    }
    // staging aliases the e0 region (consumed by fs_rel1 before accum0
    // writes e0; single stream => ordered). ent0 writes EW1/Ed/EW3h only.
    unsigned int*   stagedP = (unsigned int*)e0;                       // NB*SSTRIDE u32
    unsigned short* stagedH = (unsigned short*)(stagedP + (size_t)NB * SSTRIDE); // u16

    const int BLK = 256;

    // ---- D1: bucket scatter || layer-0 entity precompute || layer-0 rel ----
    hipMemsetAsync(ccur, 0, (size_t)NB * sizeof(int), stream);
    bke_kernel<<<BKT_BLOCKS + ENT_BLOCKS + REL_BLOCKS, 512, 0, stream>>>(
        h, r, t, ccur, stagedP, stagedH, N_EDGES,
        E, W0, Wd, bd, a0, EW1, EW3h, Ed, sh, st,
        R, Wr0, W0 + DD * DD, rel0, RW, sr);

    // ---- D2: final scatter || layer-1 relation precompute ----
    fs_rel1_kernel<<<NB + REL_BLOCKS, 512, 0, stream>>>(
        stagedP, stagedH, ccur, counts, s0, rtp,
        rel0, Wr1, W1 + DD * DD, a1, out_rel, RW1, sr1);

    if (split) {
        // ---- D3: layer-0 attention, heads [0, UHALF) ----
        accum_fused_kernel<<<UHALF / 8, BLK, 0, stream>>>(
            s0, counts, rtp, sh, sr, st, EW1, RW, EW3h, nullptr, e0, 1,
            0, UHALF);
        // ---- D4: attention heads [UHALF, N_ENT) || ent1 rows [0, UHALF) ----
        acc_ent_kernel<<<ACCB + E1HB, 512, 0, stream>>>(
            s0, counts, rtp, sh, sr, st, EW1, RW, EW3h, e0,
            W1, W1 + 2 * DD * DD, a1, EW3hb, sh1, st1);
        // ---- D5: ent1 rows [UHALF, N_ENT) ----
        ent_pre_v6<2><<<E1HB, 512, 0, stream>>>(
            e0, LD, W1, W1 + 2 * DD * DD, a1, EW1, EW3hb, sh1, st1, E1HB);
    } else {
        // serial tail (R11 semantics; tables overwritten in place)
        accum_fused_kernel<<<N_ENT / 8, BLK, 0, stream>>>(
            s0, counts, rtp, sh, sr, st, EW1, RW, EW3h, nullptr, e0, 1,
            0, N_ENT);
        ent_pre_v6<2><<<ENT_BLOCKS, 512, 0, stream>>>(
            e0, LD, W1, W1 + 2 * DD * DD, a1, EW1, EW3hb, sh1, st1, 0);
    }

    // ---- D6: layer-1 attention + fused residual ----
    accum_fused_kernel<<<N_ENT / 8, BLK, 0, stream>>>(
        s0, counts, rtp, sh1, sr1, st1, EW1, RW1, EW3hb, Ed, out_ent, 0,
        0, N_ENT);
}

// Round 14
// 335.404 us; speedup vs baseline: 1.1523x; 1.1523x over previous
//
#include <hip/hip_runtime.h>

#define N_ENT   100000
#define N_REL   500
#define DD      50
#define LD      52      // fp32 stride for sequentially-read tables (EW1/Ed/e0): 208 B
#define LD2     64      // fp32 stride for RW (L2-resident gather): 256 B
#define LDH     64      // bf16 stride for EW3h: 64 shorts = 128 B = 1 cache line
#define N_EDGES 2000000
#define T_BITS  17
#define T_MASK  0x1FFFF
#define BBITS   9                    // 512 entities per coarse bucket
#define BMASK   511
#define NB      196                  // ceil(N_ENT / 512)
#define CHUNK   4096                 // edges per bucket_scatter block (512 thr)
#define SSH     14                   // log2 staging slots per bucket
#define SSTRIDE (1 << SSH)           // 16384 slots/bucket: mean 10240, sigma~101
#define ENT_BLOCKS   2500            // N_ENT / 40
#define BKT_BLOCKS   489             // ceil(N_EDGES / CHUNK)
#define REL_BLOCKS   100             // N_REL / 5

typedef float v2f __attribute__((ext_vector_type(2)));

__device__ inline unsigned int pack_bf2(float x, float y) {
    unsigned int xu = __float_as_uint(x);
    unsigned int yu = __float_as_uint(y);
    xu = (xu + 0x7FFFu + ((xu >> 16) & 1u)) >> 16;   // round-to-nearest-even
    yu = (yu + 0x7FFFu + ((yu >> 16) & 1u)) >> 16;
    return xu | (yu << 16);
}
__device__ inline v2f unpk2(unsigned int v) {
    v2f r;
    r.x = __uint_as_float(v << 16);
    r.y = __uint_as_float(v & 0xFFFF0000u);
    return r;
}

// ---------------------------------------------------------------------------
// ent_pre body (best measured): 2x2 tiles, 512 threads, MT=40, simple k-loop.
//   Ya[m][:]  = X@Wa   fp32 stride LD  ; shOut[m] = row.a
//   Ybh[m][:] = X@Wb   bf16 stride LDH ; stOut[m] = row.a (dot from fp32)
//   Yc[m][:]  = X@Wc+bd fp32 stride LD   [NMAT==3 only]
// ---------------------------------------------------------------------------
template<int NMAT>
__device__ void ent_pre_body(float* smemF, int bid,
    const float* __restrict__ X, int ldX,
    const float* __restrict__ Wa,
    const float* __restrict__ Wb,
    const float* __restrict__ Wc,
    const float* __restrict__ bd,
    const float* __restrict__ avec,
    float* __restrict__ Ya,
    unsigned short* __restrict__ Ybh,
    float* __restrict__ Yc,
    float* __restrict__ shOut,
    float* __restrict__ stOut)
{
    constexpr int MT = 40;       // rows per block; N_ENT % MT == 0
    float* sW = smemF;                       // NMAT * DD*DD
    float* sX = sW + NMAT * DD * DD;         // MT*52
    float* sY = sX + MT * 52;                // MT*52
    float* sa = sY + MT * 52;                // DD

    const int tid = threadIdx.x;

    for (int i = tid; i < DD * DD / 4; i += 512) {
        ((float4*)sW)[i] = ((const float4*)Wa)[i];
        ((float4*)(sW + DD * DD))[i] = ((const float4*)Wb)[i];
        if (NMAT == 3) ((float4*)(sW + 2 * DD * DD))[i] = ((const float4*)Wc)[i];
    }
    if (tid < DD) sa[tid] = avec[tid];

    const int m0 = bid * MT;
    const int nX4 = MT * ldX / 4;
    const float4* xsrc = (const float4*)(X + (size_t)m0 * ldX);
    for (int i = tid; i < nX4; i += 512) ((float4*)sX)[i] = xsrc[i];
    __syncthreads();

    const bool active = (tid < 500);
    const int mp = active ? tid / 25 : 0;       // 0..19
    const int jp = active ? tid % 25 : 0;       // 0..24
    const int r0 = 2 * mp, r1 = 2 * mp + 1, j0 = 2 * jp;

    float acc[NMAT][2][2];
    #pragma unroll
    for (int t = 0; t < NMAT; t++)
        #pragma unroll
        for (int i = 0; i < 2; i++)
            #pragma unroll
            for (int c = 0; c < 2; c++) acc[t][i][c] = 0.f;

    if (active) {
        if (NMAT == 3) {
            float b0 = bd[j0], b1 = bd[j0 + 1];
            acc[2][0][0] = b0; acc[2][0][1] = b1;
            acc[2][1][0] = b0; acc[2][1][1] = b1;
        }
        const float* xr0 = &sX[r0 * ldX];
        const float* xr1 = &sX[r1 * ldX];
        for (int k = 0; k < DD; k++) {
            float x0 = xr0[k], x1 = xr1[k];
            #pragma unroll
            for (int t = 0; t < NMAT; t++) {
                float2 w = *(const float2*)&sW[t * DD * DD + k * DD + j0];
                acc[t][0][0] += x0 * w.x; acc[t][0][1] += x0 * w.y;
                acc[t][1][0] += x1 * w.x; acc[t][1][1] += x1 * w.y;
            }
        }
    }

    // zero fp32 pad cols 50,51
    if (tid < MT * 2) sY[(tid >> 1) * 52 + 50 + (tid & 1)] = 0.f;

    // ---- stage 0: Ya (fp32, stride LD) + sh dot ----
    if (active) {
        sY[r0 * 52 + j0]     = acc[0][0][0];
        sY[r0 * 52 + j0 + 1] = acc[0][0][1];
        sY[r1 * 52 + j0]     = acc[0][1][0];
        sY[r1 * 52 + j0 + 1] = acc[0][1][1];
    }
    __syncthreads();
    {
        float4* dst = (float4*)(Ya + (size_t)m0 * LD);
        for (int i = tid; i < MT * LD / 4; i += 512) dst[i] = ((const float4*)sY)[i];
        if (tid < MT) {
            const float* row = &sY[tid * 52];
            float d = 0.f;
            for (int k = 0; k < DD; k++) d += row[k] * sa[k];
            shOut[m0 + tid] = d;
        }
    }
    __syncthreads();

    // ---- stage 1: Ybh (bf16, stride LDH) + st dot (from fp32) ----
    unsigned int* sYhU = (unsigned int*)sX;       // sX dead after compute
    if (active) {
        sY[r0 * 52 + j0]     = acc[1][0][0];
        sY[r0 * 52 + j0 + 1] = acc[1][0][1];
        sY[r1 * 52 + j0]     = acc[1][1][0];
        sY[r1 * 52 + j0 + 1] = acc[1][1][1];
        sYhU[r0 * 32 + jp] = pack_bf2(acc[1][0][0], acc[1][0][1]);
        sYhU[r1 * 32 + jp] = pack_bf2(acc[1][1][0], acc[1][1][1]);
    }
    if (tid < MT * 7) sYhU[(tid / 7) * 32 + 25 + (tid % 7)] = 0u;  // bf16 pads
    __syncthreads();
    {
        float4* dst = (float4*)(Ybh + (size_t)m0 * LDH);
        for (int i = tid; i < MT * LDH * 2 / 16; i += 512) dst[i] = ((const float4*)sYhU)[i];
        if (tid < MT) {
            const float* row = &sY[tid * 52];
            float d = 0.f;
            for (int k = 0; k < DD; k++) d += row[k] * sa[k];
            stOut[m0 + tid] = d;
        }
    }

    // ---- stage 2: Yc (fp32, stride LD)  [NMAT==3] ----
    if (NMAT == 3) {
        __syncthreads();
        if (active) {
            sY[r0 * 52 + j0]     = acc[2][0][0];
            sY[r0 * 52 + j0 + 1] = acc[2][0][1];
            sY[r1 * 52 + j0]     = acc[2][1][0];
            sY[r1 * 52 + j0 + 1] = acc[2][1][1];
        }
        __syncthreads();
        float4* dst = (float4*)(Yc + (size_t)m0 * LD);
        for (int i = tid; i < MT * LD / 4; i += 512) dst[i] = ((const float4*)sY)[i];
    }
}

// standalone wrapper for layer 1
template<int NMAT>
__global__ __launch_bounds__(512) void ent_pre_v6(
    const float* __restrict__ X, int ldX,
    const float* __restrict__ Wa,
    const float* __restrict__ Wb,
    const float* __restrict__ Wc,
    const float* __restrict__ bd,
    const float* __restrict__ avec,
    float* __restrict__ Ya,
    unsigned short* __restrict__ Ybh,
    float* __restrict__ Yc,
    float* __restrict__ shOut,
    float* __restrict__ stOut)
{
    __shared__ __align__(16) float smemF[NMAT * DD * DD + 40 * 52 * 2 + 64];
    ent_pre_body<NMAT>(smemF, blockIdx.x, X, ldX, Wa, Wb, Wc, bd, avec,
                       Ya, Ybh, Yc, shOut, stOut);
}

// ---------------------------------------------------------------------------
// rel body: rel_out = (relu?) Rin @ Wr (stride ld_rel);
// RW_out = Rin @ Wmid (fp32 stride LD2); sr[m] = RW_out[m][:50].a
// 5 rows per block, uses first 250 threads (safe in 256/512-thr blocks).
// ---------------------------------------------------------------------------
__device__ void rel_body(float* smemF, int bid,
    const float* __restrict__ Rin, int ld_in,
    const float* __restrict__ Wr,
    const float* __restrict__ Wmid,
    const float* __restrict__ avec,
    int do_relu,
    float* __restrict__ rel_out, int ld_rel,
    float* __restrict__ RW_out,
    float* __restrict__ sr)
{
    float* sWr  = smemF;           // DD*DD
    float* sWm  = sWr + DD * DD;   // DD*DD
    float* sRed = sWm + DD * DD;   // 256

    for (int i = threadIdx.x; i < DD * DD; i += blockDim.x) {
        sWr[i] = Wr[i];
        sWm[i] = Wmid[i];
    }
    __syncthreads();
    const int tid = threadIdx.x;
    const bool act = (tid < 250);
    const int m = bid * 5 + tid / 50;
    const int j = tid % 50;
    float am = 0.f;
    if (act) {
        const float* x = Rin + (size_t)m * ld_in;
        float ar = 0.f;
        for (int k = 0; k < DD; k++) {
            float xv = x[k];
            ar += xv * sWr[k * DD + j];
            am += xv * sWm[k * DD + j];
        }
        if (do_relu) ar = fmaxf(ar, 0.f);
        rel_out[(size_t)m * ld_rel + j] = ar;
        RW_out[(size_t)m * LD2 + j] = am;
        if (j < LD2 - DD) RW_out[(size_t)m * LD2 + DD + j] = 0.f;
    }
    if (tid < 256) sRed[tid] = act ? am * avec[j] : 0.f;
    __syncthreads();
    if (tid < 5) {
        float d = 0.f;
        const float* p = &sRed[tid * 50];
        for (int k = 0; k < 50; k++) d += p[k];
        sr[bid * 5 + tid] = d;
    }
}

// ---------------------------------------------------------------------------
// CSR build (fixed-stride staging: NO coarse hist / scan pre-pass).
// Bucket b's staging & rtp region is [b<<SSH, (b<<SSH)+ccur[b]); ccur starts
// zeroed and bucket blocks claim slots per-bucket atomically. SSTRIDE=16384
// vs bucket size mean 10240, sigma~101 -> 60-sigma headroom.
// ---------------------------------------------------------------------------

// S1: LDS multisplit into NB staged bucket regions (512 thr, CHUNK 4096).
__device__ void bucket_body(float* smemF, int bid,
    const int* __restrict__ h,
    const int* __restrict__ r,
    const int* __restrict__ t,
    int* __restrict__ ccur,
    unsigned int* __restrict__ stagedP,
    unsigned short* __restrict__ stagedH, int nE)
{
    int* sHist = (int*)smemF;                       // NB
    int* sScan = sHist + NB;                        // 512
    int* sBase = sScan + 512;                       // NB
    int* sCur  = sBase + NB;                        // NB
    int* sGb   = sCur + NB;                         // NB
    unsigned int*   sPay = (unsigned int*)(sGb + NB);       // CHUNK
    unsigned short* sLoc = (unsigned short*)(sPay + CHUNK); // CHUNK shorts
    unsigned char*  sBkt = (unsigned char*)(sLoc + CHUNK);  // CHUNK bytes

    const int tid = threadIdx.x;
    const int e0 = bid * CHUNK;
    const int n = min(CHUNK, nE - e0);

    for (int i = tid; i < NB; i += 512) sHist[i] = 0;
    __syncthreads();

    #pragma unroll
    for (int k = 0; k < CHUNK / 512; k++) {
        int e = e0 + k * 512 + tid;
        if (e < nE) atomicAdd(&sHist[h[e] >> BBITS], 1);
    }
    __syncthreads();

    int v = (tid < NB) ? sHist[tid] : 0;
    sScan[tid] = v;
    __syncthreads();
    for (int off = 1; off < 512; off <<= 1) {
        int x = (tid >= off) ? sScan[tid - off] : 0;
        __syncthreads();
        sScan[tid] += x;
        __syncthreads();
    }
    if (tid < NB) {
        int excl = sScan[tid] - v;
        sBase[tid] = excl;
        sCur[tid] = excl;
    }
    __syncthreads();

    #pragma unroll
    for (int k = 0; k < CHUNK / 512; k++) {
        int e = e0 + k * 512 + tid;
        if (e < nE) {
            int hv = h[e];
            int b = hv >> BBITS;
            int pos = atomicAdd(&sCur[b], 1);
            sPay[pos] = ((unsigned int)r[e] << T_BITS) | (unsigned int)t[e];
            sLoc[pos] = (unsigned short)(hv & BMASK);
            sBkt[pos] = (unsigned char)b;
        }
    }
    __syncthreads();

    // claim [base, base+cnt) inside bucket tid's fixed region
    if (tid < NB) {
        int cnt = sHist[tid];
        sGb[tid] = (tid << SSH) + (cnt ? atomicAdd(&ccur[tid], cnt) : 0);
    }
    __syncthreads();

    for (int i = tid; i < n; i += 512) {
        int b = sBkt[i];
        int g = sGb[b] + (i - sBase[b]);
        stagedP[g] = sPay[i];
        stagedH[g] = sLoc[i];
    }
}

// merged dispatch: bucket_scatter (blocks 0..488) || rel_pre layer 0 (489..588)
__global__ __launch_bounds__(512) void bkt_rel0_kernel(
    const int* __restrict__ h,
    const int* __restrict__ r,
    const int* __restrict__ t,
    int* __restrict__ ccur,
    unsigned int* __restrict__ stagedP,
    unsigned short* __restrict__ stagedH, int nE,
    const float* __restrict__ R,
    const float* __restrict__ Wr0,
    const float* __restrict__ Wmid0,
    const float* __restrict__ a0,
    float* __restrict__ rel0,
    float* __restrict__ RW,
    float* __restrict__ sr)
{
    __shared__ __align__(16) float smemF[8480];
    if (blockIdx.x < BKT_BLOCKS) {
        bucket_body(smemF, blockIdx.x, h, r, t, ccur, stagedP, stagedH, nE);
    } else {
        rel_body(smemF, blockIdx.x - BKT_BLOCKS, R, DD, Wr0, Wmid0, a0, 1,
                 rel0, LD, RW, sr);
    }
}

// S2 body: one block per bucket, 512 threads. Window = fixed-stride region.
__device__ void final_scatter_body(float* smemF, int b,
    const unsigned int* __restrict__ stagedP,
    const unsigned short* __restrict__ stagedH,
    const int* __restrict__ ccnt,
    int* __restrict__ counts,
    int* __restrict__ s0,
    unsigned int* __restrict__ rtp)
{
    int* sCnt  = (int*)smemF;        // 512
    int* sScan = sCnt + 512;         // 512
    int* sOff  = sScan + 512;        // 512

    const int i0 = b << SSH;
    const int i1 = i0 + ccnt[b];
    const int tid = threadIdx.x;     // 0..511

    sCnt[tid] = 0;
    __syncthreads();

    for (int i = i0 + tid; i < i1; i += 512)
        atomicAdd(&sCnt[stagedH[i]], 1);
    __syncthreads();

    const int v = sCnt[tid];
    sScan[tid] = v;
    __syncthreads();
    for (int off = 1; off < 512; off <<= 1) {
        int x = (tid >= off) ? sScan[tid - off] : 0;
        __syncthreads();
        sScan[tid] += x;
        __syncthreads();
    }
    const int excl = sScan[tid] - v;
    sOff[tid] = excl;

    const int u = (b << BBITS) + tid;
    if (u < N_ENT) {
        counts[u] = v;
        s0[u] = i0 + excl;
    }
    __syncthreads();   // sOff fully written before use as cursors

    for (int i = i0 + tid; i < i1; i += 512) {
        unsigned int p = stagedP[i];
        int loc = stagedH[i];
        int pos = i0 + atomicAdd(&sOff[loc], 1);
        rtp[pos] = p;
    }
}

// merged dispatch: final_scatter (0..195) || ent_pre0 (196..2695) || rel1 (2696..2795)
__global__ __launch_bounds__(512) void fse_rel1_kernel(
    const unsigned int* __restrict__ stagedP,
    const unsigned short* __restrict__ stagedH,
    const int* __restrict__ ccnt,
    int* __restrict__ counts,
    int* __restrict__ s0,
    unsigned int* __restrict__ rtp,
    // ent layer-0 args
    const float* __restrict__ E,
    const float* __restrict__ W0,
    const float* __restrict__ Wd,
    const float* __restrict__ bd,
    const float* __restrict__ a0,
    float* __restrict__ EW1,
    unsigned short* __restrict__ EW3h,
    float* __restrict__ Ed,
    float* __restrict__ sh,
    float* __restrict__ st,
    // rel layer-1 args
    const float* __restrict__ rel0,
    const float* __restrict__ Wr1,
    const float* __restrict__ Wmid1,
    const float* __restrict__ a1,
    float* __restrict__ out_rel,
    float* __restrict__ RW1,
    float* __restrict__ sr1)
{
    __shared__ __align__(16) float smemF[3 * DD * DD + 40 * 52 * 2 + 64];
    if (blockIdx.x < NB) {
        final_scatter_body(smemF, blockIdx.x, stagedP, stagedH, ccnt,
                           counts, s0, rtp);
    } else if (blockIdx.x < NB + ENT_BLOCKS) {
        ent_pre_body<3>(smemF, blockIdx.x - NB, E, DD,
                        W0, W0 + 2 * DD * DD, Wd, bd, a0,
                        EW1, EW3h, Ed, sh, st);
    } else {
        rel_body(smemF, blockIdx.x - NB - ENT_BLOCKS, rel0, LD,
                 Wr1, Wmid1, a1, 0, out_rel, DD, RW1, sr1);
    }
}

// ---------------------------------------------------------------------------
// Fused score + accumulate (R8-best): two heads per wave + packed dual-fp32
// math + 3-deep software pipeline. No block-wide coupling (waves independent).
// Pads (cols 50+) are zero in all tables -> pad outputs are exactly 0.
// ---------------------------------------------------------------------------
__global__ __launch_bounds__(256) void accum_fused_kernel(
    const int* __restrict__ s0v,
    const int* __restrict__ counts,
    const unsigned int* __restrict__ rtp,
    const float* __restrict__ sh,
    const float* __restrict__ sr,
    const float* __restrict__ st,
    const float* __restrict__ EW1,
    const float* __restrict__ RW,
    const unsigned short* __restrict__ EW3h,
    const float* __restrict__ base,
    float* __restrict__ outp, int full_ld)
{
    const int wid = (blockIdx.x * blockDim.x + threadIdx.x) >> 6;  // wave id
    if (2 * wid >= N_ENT) return;
    const int lane  = threadIdx.x & 63;
    const int half  = lane >> 5;       // which head of the pair
    const int hlane = lane & 31;
    const int eg = hlane >> 3;         // 0..3 edge group
    const int q  = hlane & 7;          // 0..7 col group
    const int sbase = half << 5;       // shuffle base of this half
    const unsigned qh = (unsigned)q << 4;    // byte offset into EW3h row
    const unsigned qr = (unsigned)q << 5;    // byte offset into RW row

    const int u = 2 * wid + half;      // N_ENT even -> always < N_ENT
    const int b = s0v[u];
    const int c = counts[u];
    const float shu = sh[u];

    const char* __restrict__ pH = (const char*)EW3h;
    const char* __restrict__ pR = (const char*)RW;
    const char* __restrict__ pS = (const char*)sr;
    const char* __restrict__ pT = (const char*)st;

    v2f acc2[4];
    #pragma unroll
    for (int k = 0; k < 4; k++) { acc2[k].x = 0.f; acc2[k].y = 0.f; }
    float asum = 0.f;

    for (int i0 = 0; i0 < c; i0 += 32) {
        const int cb = min(32, c - i0);            // edges in this batch
        // ---- score phase: hlane scores edge i0+hlane of its head ----
        const int e = i0 + hlane;
        const unsigned w = rtp[b + min(e, c - 1)];
        float ex = 0.f;
        if (e < c) {
            float srv = *(const float*)(pS + ((w >> T_BITS) << 2));
            float stv = *(const float*)(pT + ((w & T_MASK) << 2));
            float sc = shu + srv + stv;
            sc = sc >= 0.f ? sc : 0.2f * sc;
            ex = __expf(sc);
        }
        asum += ex;

        const int nst = (cb + 3) >> 2;             // 4 edges per step per head

#define LOADSTEP(S, TH, VA, VB, EX) {                                   \
        const int _src = sbase + min((S) * 4 + eg, cb - 1);             \
        const unsigned _wv = (unsigned)__shfl((int)w, _src);            \
        EX = __shfl(ex, _src);                                          \
        const unsigned _oH = ((_wv & T_MASK) << 7) | qh;                \
        const unsigned _oR = ((_wv >> T_BITS) << 8) | qr;               \
        TH = *(const uint4*)(pH + _oH);                                 \
        VA = *(const float4*)(pR + _oR);                                \
        VB = *(const float4*)(pR + _oR + 16); }

        uint4 th0, th1; float4 va0, vb0, va1, vb1; float ex0, ex1;
        LOADSTEP(0, th0, va0, vb0, ex0)
        LOADSTEP(1, th1, va1, vb1, ex1)

        for (int s = 0; s < nst; s++) {
            uint4 thn; float4 van, vbn; float exn;
            LOADSTEP(s + 2, thn, van, vbn, exn)    // prefetch 2 steps ahead

            const float exv = (s * 4 + eg < cb) ? ex0 : 0.f;
            v2f ex2; ex2.x = exv; ex2.y = exv;
            v2f p01; p01.x = va0.x; p01.y = va0.y;
            v2f p23; p23.x = va0.z; p23.y = va0.w;
            v2f p45; p45.x = vb0.x; p45.y = vb0.y;
            v2f p67; p67.x = vb0.z; p67.y = vb0.w;
            acc2[0] += ex2 * (p01 + unpk2(th0.x));   // pk_add + pk_fma
            acc2[1] += ex2 * (p23 + unpk2(th0.y));
            acc2[2] += ex2 * (p45 + unpk2(th0.z));
            acc2[3] += ex2 * (p67 + unpk2(th0.w));

            th0 = th1; va0 = va1; vb0 = vb1; ex0 = ex1;
            th1 = thn; va1 = van; vb1 = vbn; ex1 = exn;
        }
#undef LOADSTEP
    }

    // epilogue prefetch: issue EW1/base row loads before the fold so their
    // latency hides under the shuffle reduction
    const int ej = 8 * hlane;
    const bool ep = (hlane < 8) && (ej < LD);
    const bool efull = ep && (ej < 48);
    float4 w1a, w1b, ba, bb;
    if (ep) {
        const float* e1 = EW1 + (size_t)u * LD + (efull ? ej : 48);
        w1a = *(const float4*)e1;
        if (efull) w1b = *(const float4*)(e1 + 4);
        if (base) {
            const float* bp = base + (size_t)u * LD + (efull ? ej : 48);
            ba = *(const float4*)bp;
            if (efull) bb = *(const float4*)(bp + 4);
        }
    }

    // fold within each 32-lane half: acc over 4 edge-groups; asum over 32
    float acc[8];
    #pragma unroll
    for (int k = 0; k < 4; k++) { acc[2 * k] = acc2[k].x; acc[2 * k + 1] = acc2[k].y; }
    #pragma unroll
    for (int off = 16; off >= 8; off >>= 1) {
        #pragma unroll
        for (int k = 0; k < 8; k++) acc[k] += __shfl_down(acc[k], off, 32);
        asum += __shfl_down(asum, off, 32);
    }
    asum += __shfl_xor(asum, 4);
    asum += __shfl_xor(asum, 2);
    asum += __shfl_xor(asum, 1);

    if (hlane >= 8) return;            // lanes 0..7 of each half hold cols
    const int j0 = 8 * hlane;
    if (j0 >= LD) return;              // hlane 7 -> cols 56.. out of range

    if (asum > 0.f) {
        float inv = 1.f / asum;
        if (j0 < 48) {
            acc[0] = w1a.x + acc[0] * inv; acc[1] = w1a.y + acc[1] * inv;
            acc[2] = w1a.z + acc[2] * inv; acc[3] = w1a.w + acc[3] * inv;
            acc[4] = w1b.x + acc[4] * inv; acc[5] = w1b.y + acc[5] * inv;
            acc[6] = w1b.z + acc[6] * inv; acc[7] = w1b.w + acc[7] * inv;
        } else {  // j0 == 48: cols 48,49 real; 50,51 pads (zero everywhere)
            acc[0] = w1a.x + acc[0] * inv; acc[1] = w1a.y + acc[1] * inv;
            acc[2] = w1a.z + acc[2] * inv; acc[3] = w1a.w + acc[3] * inv;
        }
    }  // else: empty segment -> 0, matching ref
    if (base) {
        if (j0 < 48) {
            acc[0] += ba.x; acc[1] += ba.y; acc[2] += ba.z; acc[3] += ba.w;
            acc[4] += bb.x; acc[5] += bb.y; acc[6] += bb.z; acc[7] += bb.w;
        } else {
            acc[0] += ba.x; acc[1] += ba.y; acc[2] += ba.z; acc[3] += ba.w;
        }
    }
    if (full_ld) {                      // stride LD=52, 16B-aligned
        if (j0 < 48) {
            *(float4*)(outp + (size_t)u * LD + j0) =
                make_float4(acc[0], acc[1], acc[2], acc[3]);
            *(float4*)(outp + (size_t)u * LD + j0 + 4) =
                make_float4(acc[4], acc[5], acc[6], acc[7]);
        } else {                        // cols 48..51 (50,51 are exact zeros)
            *(float4*)(outp + (size_t)u * LD + 48) =
                make_float4(acc[0], acc[1], acc[2], acc[3]);
        }
    } else {                            // stride DD=50, rows only 8B-aligned
        float* row = outp + (size_t)u * DD;
        if (j0 < 48) {
            *(float2*)(row + j0)     = make_float2(acc[0], acc[1]);
            *(float2*)(row + j0 + 2) = make_float2(acc[2], acc[3]);
            *(float2*)(row + j0 + 4) = make_float2(acc[4], acc[5]);
            *(float2*)(row + j0 + 6) = make_float2(acc[6], acc[7]);
        } else {
            *(float2*)(row + 48) = make_float2(acc[0], acc[1]);
        }
    }
}

// ---------------------------------------------------------------------------
extern "C" void kernel_launch(void* const* d_in, const int* in_sizes, int n_in,
                              void* d_out, int out_size, void* d_ws, size_t ws_size,
                              hipStream_t stream)
{
    const int*   h   = (const int*)d_in[0];
    const int*   r   = (const int*)d_in[1];
    const int*   t   = (const int*)d_in[2];
    const float* E   = (const float*)d_in[3];
    const float* R   = (const float*)d_in[4];
    const float* W0  = (const float*)d_in[5];
    const float* a0  = (const float*)d_in[6];
    const float* Wr0 = (const float*)d_in[7];
    const float* W1  = (const float*)d_in[8];
    const float* a1  = (const float*)d_in[9];
    const float* Wr1 = (const float*)d_in[10];
    const float* Wd  = (const float*)d_in[11];
    const float* bd  = (const float*)d_in[12];

    float* out_ent = (float*)d_out;                 // [N_ENT, DD] stride DD
    float* out_rel = out_ent + (size_t)N_ENT * DD;  // [N_REL, DD] stride DD

    // workspace layout (~92 MB)
    float* ws_f  = (float*)d_ws;
    float* EW1   = ws_f;                                   // N_ENT*LD
    float* Ed    = EW1  + (size_t)N_ENT * LD;              // N_ENT*LD
    float* e0    = Ed   + (size_t)N_ENT * LD;              // N_ENT*LD
    unsigned short* EW3h = (unsigned short*)(e0 + (size_t)N_ENT * LD);  // N_ENT*LDH bf16
    float* RW    = (float*)(EW3h + (size_t)N_ENT * LDH);   // N_REL*LD2
    float* RW1   = RW   + (size_t)N_REL * LD2;             // N_REL*LD2
    float* rel0  = RW1  + (size_t)N_REL * LD2;             // N_REL*LD
    float* sh    = rel0 + (size_t)N_REL * LD;              // N_ENT
    float* st    = sh   + N_ENT;                           // N_ENT
    float* sr    = st   + N_ENT;                           // N_REL
    float* sr1   = sr   + N_REL;                           // N_REL
    int* counts  = (int*)(sr1 + N_REL);                    // N_ENT
    int* s0      = counts + N_ENT;                         // N_ENT
    int* ccur    = s0 + N_ENT;                             // NB
    unsigned int* rtp    = (unsigned int*)(ccur + NB);     // NB*SSTRIDE (12.8 MB)
    // staging aliases the e0 region: e0 is first written by accum0, which
    // launches strictly after fse_rel1 (final_scatter) consumed the staging
    // (single stream => ordered). ent_pre0 (co-dispatched with final_scatter)
    // writes EW1/Ed/EW3h only — no overlap with e0.
    // stagedP (12.84 MB) + stagedH (6.42 MB) = 19.26 MB < e0's 20.8 MB.
    unsigned int*   stagedP = (unsigned int*)e0;                       // NB*SSTRIDE u32
    unsigned short* stagedH = (unsigned short*)(stagedP + (size_t)NB * SSTRIDE); // NB*SSTRIDE u16

    const int BLK = 256;
    const int gW  = (N_ENT / 2 + 3) / 4;         // accum: 1 wave per 2 heads

    // ---- bucket scatter || layer-0 relation precompute ----
    hipMemsetAsync(ccur, 0, (size_t)NB * sizeof(int), stream);
    bkt_rel0_kernel<<<BKT_BLOCKS + REL_BLOCKS, 512, 0, stream>>>(
        h, r, t, ccur, stagedP, stagedH, N_EDGES,
        R, Wr0, W0 + DD * DD, a0, rel0, RW, sr);

    // ---- final scatter || layer-0 entity precompute || layer-1 rel ----
    fse_rel1_kernel<<<NB + ENT_BLOCKS + REL_BLOCKS, 512, 0, stream>>>(
        stagedP, stagedH, ccur, counts, s0, rtp,
        E, W0, Wd, bd, a0, EW1, EW3h, Ed, sh, st,
        rel0, Wr1, W1 + DD * DD, a1, out_rel, RW1, sr1);

    // ---- layer 0 attention (fused score+softmax+accumulate) ----
    accum_fused_kernel<<<gW, BLK, 0, stream>>>(s0, counts, rtp, sh, sr, st,
                                               EW1, RW, EW3h, nullptr, e0, 1);

    // ---- layer 1 entity precompute ----
    ent_pre_v6<2><<<ENT_BLOCKS, 512, 0, stream>>>(e0, LD, W1, W1 + 2 * DD * DD,
                                                  nullptr, nullptr, a1,
                                                  EW1, EW3h, nullptr, sh, st);

    // ---- layer 1 attention + fused residual ----
    accum_fused_kernel<<<gW, BLK, 0, stream>>>(s0, counts, rtp, sh, sr1, st,
                                               EW1, RW1, EW3h, Ed, out_ent, 0);
}

// Round 15
// 312.756 us; speedup vs baseline: 1.2358x; 1.0724x over previous
//
#include <hip/hip_runtime.h>

#define N_ENT   100000
#define N_REL   500
#define DD      50
#define LD      52      // fp32 stride for sequentially-read tables (EW1/Ed/e0): 208 B
#define LD2     64      // fp32 stride for RW (L2-resident gather): 256 B
#define LDH     64      // bf16 stride for EW3h: 64 shorts = 128 B = 1 cache line
#define N_EDGES 2000000
#define T_BITS  17
#define T_MASK  0x1FFFF
#define BBITS   9                    // 512 entities per coarse bucket
#define BMASK   511
#define NB      196                  // ceil(N_ENT / 512)
#define CHUNK   4096                 // edges per bucket_scatter block (512 thr)
#define SSH     14                   // log2 staging slots per bucket
#define SSTRIDE (1 << SSH)           // 16384 slots/bucket: mean 10240, sigma~101
#define ENT_BLOCKS   1250            // N_ENT / 80 (MT=80, 4-row tiles)
#define BKT_BLOCKS   489             // ceil(N_EDGES / CHUNK)
#define REL_BLOCKS   100             // N_REL / 5

typedef float v2f __attribute__((ext_vector_type(2)));

__device__ inline unsigned int pack_bf2(float x, float y) {
    unsigned int xu = __float_as_uint(x);
    unsigned int yu = __float_as_uint(y);
    xu = (xu + 0x7FFFu + ((xu >> 16) & 1u)) >> 16;   // round-to-nearest-even
    yu = (yu + 0x7FFFu + ((yu >> 16) & 1u)) >> 16;
    return xu | (yu << 16);
}
__device__ inline v2f unpk2(unsigned int v) {
    v2f r;
    r.x = __uint_as_float(v << 16);
    r.y = __uint_as_float(v & 0xFFFF0000u);
    return r;
}

// ---------------------------------------------------------------------------
// ent_pre body v7: 4x2 tiles, MT=80, 512 threads. Per k: 7 LDS reads / 24 FMA
// vs the 2x2 tile's 5 / 12 — 37% fewer LDS-pipe cycles per output (the
// measured limiter: R5 16-wave and R6 24-wave both ~61.5us => not TLP-bound).
//   Ya[m][:]  = X@Wa   fp32 stride LD  ; shOut[m] = row.a
//   Ybh[m][:] = X@Wb   bf16 stride LDH ; stOut[m] = row.a (dot from fp32)
//   Yc[m][:]  = X@Wc+bd fp32 stride LD   [NMAT==3 only]
// ---------------------------------------------------------------------------
template<int NMAT>
__device__ void ent_pre_body(float* smemF, int bid,
    const float* __restrict__ X, int ldX,
    const float* __restrict__ Wa,
    const float* __restrict__ Wb,
    const float* __restrict__ Wc,
    const float* __restrict__ bd,
    const float* __restrict__ avec,
    float* __restrict__ Ya,
    unsigned short* __restrict__ Ybh,
    float* __restrict__ Yc,
    float* __restrict__ shOut,
    float* __restrict__ stOut)
{
    constexpr int MT = 80;       // rows per block; N_ENT % MT == 0
    float* sW = smemF;                       // NMAT * DD*DD
    float* sX = sW + NMAT * DD * DD;         // MT*52
    float* sY = sX + MT * 52;                // MT*52
    float* sa = sY + MT * 52;                // DD

    const int tid = threadIdx.x;

    for (int i = tid; i < DD * DD / 4; i += 512) {
        ((float4*)sW)[i] = ((const float4*)Wa)[i];
        ((float4*)(sW + DD * DD))[i] = ((const float4*)Wb)[i];
        if (NMAT == 3) ((float4*)(sW + 2 * DD * DD))[i] = ((const float4*)Wc)[i];
    }
    if (tid < DD) sa[tid] = avec[tid];

    const int m0 = bid * MT;
    const int nX4 = MT * ldX / 4;
    const float4* xsrc = (const float4*)(X + (size_t)m0 * ldX);
    for (int i = tid; i < nX4; i += 512) ((float4*)sX)[i] = xsrc[i];
    __syncthreads();

    const bool active = (tid < 500);
    const int mp = active ? tid / 25 : 0;       // 0..19 (4 rows each)
    const int jp = active ? tid % 25 : 0;       // 0..24 (2 cols each)
    const int r0 = 4 * mp, j0 = 2 * jp;

    float acc[NMAT][4][2];
    #pragma unroll
    for (int t = 0; t < NMAT; t++)
        #pragma unroll
        for (int i = 0; i < 4; i++) {
            acc[t][i][0] = 0.f; acc[t][i][1] = 0.f;
        }

    if (active) {
        if (NMAT == 3) {
            float b0 = bd[j0], b1 = bd[j0 + 1];
            #pragma unroll
            for (int i = 0; i < 4; i++) { acc[2][i][0] = b0; acc[2][i][1] = b1; }
        }
        const float* xr = &sX[r0 * ldX];
        for (int k = 0; k < DD; k++) {
            float x0 = xr[k];
            float x1 = xr[k + ldX];
            float x2 = xr[k + 2 * ldX];
            float x3 = xr[k + 3 * ldX];
            #pragma unroll
            for (int t = 0; t < NMAT; t++) {
                float2 w = *(const float2*)&sW[t * DD * DD + k * DD + j0];
                acc[t][0][0] += x0 * w.x; acc[t][0][1] += x0 * w.y;
                acc[t][1][0] += x1 * w.x; acc[t][1][1] += x1 * w.y;
                acc[t][2][0] += x2 * w.x; acc[t][2][1] += x2 * w.y;
                acc[t][3][0] += x3 * w.x; acc[t][3][1] += x3 * w.y;
            }
        }
    }

    // zero fp32 pad cols 50,51 (MT*2 = 160 slots)
    if (tid < MT * 2) sY[(tid >> 1) * 52 + 50 + (tid & 1)] = 0.f;

    // ---- stage 0: Ya (fp32, stride LD) + sh dot ----
    if (active) {
        #pragma unroll
        for (int i = 0; i < 4; i++) {
            sY[(r0 + i) * 52 + j0]     = acc[0][i][0];
            sY[(r0 + i) * 52 + j0 + 1] = acc[0][i][1];
        }
    }
    __syncthreads();
    {
        float4* dst = (float4*)(Ya + (size_t)m0 * LD);
        for (int i = tid; i < MT * LD / 4; i += 512) dst[i] = ((const float4*)sY)[i];
        if (tid < MT) {
            const float* row = &sY[tid * 52];
            float d = 0.f;
            for (int k = 0; k < DD; k++) d += row[k] * sa[k];
            shOut[m0 + tid] = d;
        }
    }
    __syncthreads();

    // ---- stage 1: Ybh (bf16, stride LDH) + st dot (from fp32) ----
    unsigned int* sYhU = (unsigned int*)sX;       // sX dead after compute
    if (active) {
        #pragma unroll
        for (int i = 0; i < 4; i++) {
            sY[(r0 + i) * 52 + j0]     = acc[1][i][0];
            sY[(r0 + i) * 52 + j0 + 1] = acc[1][i][1];
            sYhU[(r0 + i) * 32 + jp] = pack_bf2(acc[1][i][0], acc[1][i][1]);
        }
    }
    for (int i = tid; i < MT * 7; i += 512)
        sYhU[(i / 7) * 32 + 25 + (i % 7)] = 0u;   // bf16 pads
    __syncthreads();
    {
        float4* dst = (float4*)(Ybh + (size_t)m0 * LDH);
        for (int i = tid; i < MT * LDH * 2 / 16; i += 512) dst[i] = ((const float4*)sYhU)[i];
        if (tid < MT) {
            const float* row = &sY[tid * 52];
            float d = 0.f;
            for (int k = 0; k < DD; k++) d += row[k] * sa[k];
            stOut[m0 + tid] = d;
        }
    }

    // ---- stage 2: Yc (fp32, stride LD)  [NMAT==3] ----
    if (NMAT == 3) {
        __syncthreads();
        if (active) {
            #pragma unroll
            for (int i = 0; i < 4; i++) {
                sY[(r0 + i) * 52 + j0]     = acc[2][i][0];
                sY[(r0 + i) * 52 + j0 + 1] = acc[2][i][1];
            }
        }
        __syncthreads();
        float4* dst = (float4*)(Yc + (size_t)m0 * LD);
        for (int i = tid; i < MT * LD / 4; i += 512) dst[i] = ((const float4*)sY)[i];
    }
}

// standalone wrapper for layer 1
template<int NMAT>
__global__ __launch_bounds__(512) void ent_pre_v6(
    const float* __restrict__ X, int ldX,
    const float* __restrict__ Wa,
    const float* __restrict__ Wb,
    const float* __restrict__ Wc,
    const float* __restrict__ bd,
    const float* __restrict__ avec,
    float* __restrict__ Ya,
    unsigned short* __restrict__ Ybh,
    float* __restrict__ Yc,
    float* __restrict__ shOut,
    float* __restrict__ stOut)
{
    __shared__ __align__(16) float smemF[NMAT * DD * DD + 80 * 52 * 2 + 64];
    ent_pre_body<NMAT>(smemF, blockIdx.x, X, ldX, Wa, Wb, Wc, bd, avec,
                       Ya, Ybh, Yc, shOut, stOut);
}

// ---------------------------------------------------------------------------
// rel body: rel_out = (relu?) Rin @ Wr (stride ld_rel);
// RW_out = Rin @ Wmid (fp32 stride LD2); sr[m] = RW_out[m][:50].a
// 5 rows per block, uses first 250 threads (safe in 256/512-thr blocks).
// ---------------------------------------------------------------------------
__device__ void rel_body(float* smemF, int bid,
    const float* __restrict__ Rin, int ld_in,
    const float* __restrict__ Wr,
    const float* __restrict__ Wmid,
    const float* __restrict__ avec,
    int do_relu,
    float* __restrict__ rel_out, int ld_rel,
    float* __restrict__ RW_out,
    float* __restrict__ sr)
{
    float* sWr  = smemF;           // DD*DD
    float* sWm  = sWr + DD * DD;   // DD*DD
    float* sRed = sWm + DD * DD;   // 256

    for (int i = threadIdx.x; i < DD * DD; i += blockDim.x) {
        sWr[i] = Wr[i];
        sWm[i] = Wmid[i];
    }
    __syncthreads();
    const int tid = threadIdx.x;
    const bool act = (tid < 250);
    const int m = bid * 5 + tid / 50;
    const int j = tid % 50;
    float am = 0.f;
    if (act) {
        const float* x = Rin + (size_t)m * ld_in;
        float ar = 0.f;
        for (int k = 0; k < DD; k++) {
            float xv = x[k];
            ar += xv * sWr[k * DD + j];
            am += xv * sWm[k * DD + j];
        }
        if (do_relu) ar = fmaxf(ar, 0.f);
        rel_out[(size_t)m * ld_rel + j] = ar;
        RW_out[(size_t)m * LD2 + j] = am;
        if (j < LD2 - DD) RW_out[(size_t)m * LD2 + DD + j] = 0.f;
    }
    if (tid < 256) sRed[tid] = act ? am * avec[j] : 0.f;
    __syncthreads();
    if (tid < 5) {
        float d = 0.f;
        const float* p = &sRed[tid * 50];
        for (int k = 0; k < 50; k++) d += p[k];
        sr[bid * 5 + tid] = d;
    }
}

// ---------------------------------------------------------------------------
// CSR build (fixed-stride staging: NO coarse hist / scan pre-pass).
// Bucket b's staging & rtp region is [b<<SSH, (b<<SSH)+ccur[b]); ccur starts
// zeroed and bucket blocks claim slots per-bucket atomically. SSTRIDE=16384
// vs bucket size mean 10240, sigma~101 -> 60-sigma headroom.
// ---------------------------------------------------------------------------

// S1: LDS multisplit into NB staged bucket regions (512 thr, CHUNK 4096).
__device__ void bucket_body(float* smemF, int bid,
    const int* __restrict__ h,
    const int* __restrict__ r,
    const int* __restrict__ t,
    int* __restrict__ ccur,
    unsigned int* __restrict__ stagedP,
    unsigned short* __restrict__ stagedH, int nE)
{
    int* sHist = (int*)smemF;                       // NB
    int* sScan = sHist + NB;                        // 512
    int* sBase = sScan + 512;                       // NB
    int* sCur  = sBase + NB;                        // NB
    int* sGb   = sCur + NB;                         // NB
    unsigned int*   sPay = (unsigned int*)(sGb + NB);       // CHUNK
    unsigned short* sLoc = (unsigned short*)(sPay + CHUNK); // CHUNK shorts
    unsigned char*  sBkt = (unsigned char*)(sLoc + CHUNK);  // CHUNK bytes

    const int tid = threadIdx.x;
    const int e0 = bid * CHUNK;
    const int n = min(CHUNK, nE - e0);

    for (int i = tid; i < NB; i += 512) sHist[i] = 0;
    __syncthreads();

    #pragma unroll
    for (int k = 0; k < CHUNK / 512; k++) {
        int e = e0 + k * 512 + tid;
        if (e < nE) atomicAdd(&sHist[h[e] >> BBITS], 1);
    }
    __syncthreads();

    int v = (tid < NB) ? sHist[tid] : 0;
    sScan[tid] = v;
    __syncthreads();
    for (int off = 1; off < 512; off <<= 1) {
        int x = (tid >= off) ? sScan[tid - off] : 0;
        __syncthreads();
        sScan[tid] += x;
        __syncthreads();
    }
    if (tid < NB) {
        int excl = sScan[tid] - v;
        sBase[tid] = excl;
        sCur[tid] = excl;
    }
    __syncthreads();

    #pragma unroll
    for (int k = 0; k < CHUNK / 512; k++) {
        int e = e0 + k * 512 + tid;
        if (e < nE) {
            int hv = h[e];
            int b = hv >> BBITS;
            int pos = atomicAdd(&sCur[b], 1);
            sPay[pos] = ((unsigned int)r[e] << T_BITS) | (unsigned int)t[e];
            sLoc[pos] = (unsigned short)(hv & BMASK);
            sBkt[pos] = (unsigned char)b;
        }
    }
    __syncthreads();

    // claim [base, base+cnt) inside bucket tid's fixed region
    if (tid < NB) {
        int cnt = sHist[tid];
        sGb[tid] = (tid << SSH) + (cnt ? atomicAdd(&ccur[tid], cnt) : 0);
    }
    __syncthreads();

    for (int i = tid; i < n; i += 512) {
        int b = sBkt[i];
        int g = sGb[b] + (i - sBase[b]);
        stagedP[g] = sPay[i];
        stagedH[g] = sLoc[i];
    }
}

// merged dispatch: bucket_scatter (blocks 0..488) || rel_pre layer 0 (489..588)
__global__ __launch_bounds__(512) void bkt_rel0_kernel(
    const int* __restrict__ h,
    const int* __restrict__ r,
    const int* __restrict__ t,
    int* __restrict__ ccur,
    unsigned int* __restrict__ stagedP,
    unsigned short* __restrict__ stagedH, int nE,
    const float* __restrict__ R,
    const float* __restrict__ Wr0,
    const float* __restrict__ Wmid0,
    const float* __restrict__ a0,
    float* __restrict__ rel0,
    float* __restrict__ RW,
    float* __restrict__ sr)
{
    __shared__ __align__(16) float smemF[8480];
    if (blockIdx.x < BKT_BLOCKS) {
        bucket_body(smemF, blockIdx.x, h, r, t, ccur, stagedP, stagedH, nE);
    } else {
        rel_body(smemF, blockIdx.x - BKT_BLOCKS, R, DD, Wr0, Wmid0, a0, 1,
                 rel0, LD, RW, sr);
    }
}

// S2 body: one block per bucket, 512 threads. Window = fixed-stride region.
__device__ void final_scatter_body(float* smemF, int b,
    const unsigned int* __restrict__ stagedP,
    const unsigned short* __restrict__ stagedH,
    const int* __restrict__ ccnt,
    int* __restrict__ counts,
    int* __restrict__ s0,
    unsigned int* __restrict__ rtp)
{
    int* sCnt  = (int*)smemF;        // 512
    int* sScan = sCnt + 512;         // 512
    int* sOff  = sScan + 512;        // 512

    const int i0 = b << SSH;
    const int i1 = i0 + ccnt[b];
    const int tid = threadIdx.x;     // 0..511

    sCnt[tid] = 0;
    __syncthreads();

    for (int i = i0 + tid; i < i1; i += 512)
        atomicAdd(&sCnt[stagedH[i]], 1);
    __syncthreads();

    const int v = sCnt[tid];
    sScan[tid] = v;
    __syncthreads();
    for (int off = 1; off < 512; off <<= 1) {
        int x = (tid >= off) ? sScan[tid - off] : 0;
        __syncthreads();
        sScan[tid] += x;
        __syncthreads();
    }
    const int excl = sScan[tid] - v;
    sOff[tid] = excl;

    const int u = (b << BBITS) + tid;
    if (u < N_ENT) {
        counts[u] = v;
        s0[u] = i0 + excl;
    }
    __syncthreads();   // sOff fully written before use as cursors

    for (int i = i0 + tid; i < i1; i += 512) {
        unsigned int p = stagedP[i];
        int loc = stagedH[i];
        int pos = i0 + atomicAdd(&sOff[loc], 1);
        rtp[pos] = p;
    }
}

// merged dispatch: final_scatter (0..195) || ent_pre0 (196..1445) || rel1 (1446..1545)
__global__ __launch_bounds__(512) void fse_rel1_kernel(
    const unsigned int* __restrict__ stagedP,
    const unsigned short* __restrict__ stagedH,
    const int* __restrict__ ccnt,
    int* __restrict__ counts,
    int* __restrict__ s0,
    unsigned int* __restrict__ rtp,
    // ent layer-0 args
    const float* __restrict__ E,
    const float* __restrict__ W0,
    const float* __restrict__ Wd,
    const float* __restrict__ bd,
    const float* __restrict__ a0,
    float* __restrict__ EW1,
    unsigned short* __restrict__ EW3h,
    float* __restrict__ Ed,
    float* __restrict__ sh,
    float* __restrict__ st,
    // rel layer-1 args
    const float* __restrict__ rel0,
    const float* __restrict__ Wr1,
    const float* __restrict__ Wmid1,
    const float* __restrict__ a1,
    float* __restrict__ out_rel,
    float* __restrict__ RW1,
    float* __restrict__ sr1)
{
    __shared__ __align__(16) float smemF[3 * DD * DD + 80 * 52 * 2 + 64];
    if (blockIdx.x < NB) {
        final_scatter_body(smemF, blockIdx.x, stagedP, stagedH, ccnt,
                           counts, s0, rtp);
    } else if (blockIdx.x < NB + ENT_BLOCKS) {
        ent_pre_body<3>(smemF, blockIdx.x - NB, E, DD,
                        W0, W0 + 2 * DD * DD, Wd, bd, a0,
                        EW1, EW3h, Ed, sh, st);
    } else {
        rel_body(smemF, blockIdx.x - NB - ENT_BLOCKS, rel0, LD,
                 Wr1, Wmid1, a1, 0, out_rel, DD, RW1, sr1);
    }
}

// ---------------------------------------------------------------------------
// Fused score + accumulate (R8-best): two heads per wave + packed dual-fp32
// math + 3-deep software pipeline. No block-wide coupling (waves independent).
// Pads (cols 50+) are zero in all tables -> pad outputs are exactly 0.
// ---------------------------------------------------------------------------
__global__ __launch_bounds__(256) void accum_fused_kernel(
    const int* __restrict__ s0v,
    const int* __restrict__ counts,
    const unsigned int* __restrict__ rtp,
    const float* __restrict__ sh,
    const float* __restrict__ sr,
    const float* __restrict__ st,
    const float* __restrict__ EW1,
    const float* __restrict__ RW,
    const unsigned short* __restrict__ EW3h,
    const float* __restrict__ base,
    float* __restrict__ outp, int full_ld)
{
    const int wid = (blockIdx.x * blockDim.x + threadIdx.x) >> 6;  // wave id
    if (2 * wid >= N_ENT) return;
    const int lane  = threadIdx.x & 63;
    const int half  = lane >> 5;       // which head of the pair
    const int hlane = lane & 31;
    const int eg = hlane >> 3;         // 0..3 edge group
    const int q  = hlane & 7;          // 0..7 col group
    const int sbase = half << 5;       // shuffle base of this half
    const unsigned qh = (unsigned)q << 4;    // byte offset into EW3h row
    const unsigned qr = (unsigned)q << 5;    // byte offset into RW row

    const int u = 2 * wid + half;      // N_ENT even -> always < N_ENT
    const int b = s0v[u];
    const int c = counts[u];
    const float shu = sh[u];

    const char* __restrict__ pH = (const char*)EW3h;
    const char* __restrict__ pR = (const char*)RW;
    const char* __restrict__ pS = (const char*)sr;
    const char* __restrict__ pT = (const char*)st;

    v2f acc2[4];
    #pragma unroll
    for (int k = 0; k < 4; k++) { acc2[k].x = 0.f; acc2[k].y = 0.f; }
    float asum = 0.f;

    for (int i0 = 0; i0 < c; i0 += 32) {
        const int cb = min(32, c - i0);            // edges in this batch
        // ---- score phase: hlane scores edge i0+hlane of its head ----
        const int e = i0 + hlane;
        const unsigned w = rtp[b + min(e, c - 1)];
        float ex = 0.f;
        if (e < c) {
            float srv = *(const float*)(pS + ((w >> T_BITS) << 2));
            float stv = *(const float*)(pT + ((w & T_MASK) << 2));
            float sc = shu + srv + stv;
            sc = sc >= 0.f ? sc : 0.2f * sc;
            ex = __expf(sc);
        }
        asum += ex;

        const int nst = (cb + 3) >> 2;             // 4 edges per step per head

#define LOADSTEP(S, TH, VA, VB, EX) {                                   \
        const int _src = sbase + min((S) * 4 + eg, cb - 1);             \
        const unsigned _wv = (unsigned)__shfl((int)w, _src);            \
        EX = __shfl(ex, _src);                                          \
        const unsigned _oH = ((_wv & T_MASK) << 7) | qh;                \
        const unsigned _oR = ((_wv >> T_BITS) << 8) | qr;               \
        TH = *(const uint4*)(pH + _oH);                                 \
        VA = *(const float4*)(pR + _oR);                                \
        VB = *(const float4*)(pR + _oR + 16); }

        uint4 th0, th1; float4 va0, vb0, va1, vb1; float ex0, ex1;
        LOADSTEP(0, th0, va0, vb0, ex0)
        LOADSTEP(1, th1, va1, vb1, ex1)

        for (int s = 0; s < nst; s++) {
            uint4 thn; float4 van, vbn; float exn;
            LOADSTEP(s + 2, thn, van, vbn, exn)    // prefetch 2 steps ahead

            const float exv = (s * 4 + eg < cb) ? ex0 : 0.f;
            v2f ex2; ex2.x = exv; ex2.y = exv;
            v2f p01; p01.x = va0.x; p01.y = va0.y;
            v2f p23; p23.x = va0.z; p23.y = va0.w;
            v2f p45; p45.x = vb0.x; p45.y = vb0.y;
            v2f p67; p67.x = vb0.z; p67.y = vb0.w;
            acc2[0] += ex2 * (p01 + unpk2(th0.x));   // pk_add + pk_fma
            acc2[1] += ex2 * (p23 + unpk2(th0.y));
            acc2[2] += ex2 * (p45 + unpk2(th0.z));
            acc2[3] += ex2 * (p67 + unpk2(th0.w));

            th0 = th1; va0 = va1; vb0 = vb1; ex0 = ex1;
            th1 = thn; va1 = van; vb1 = vbn; ex1 = exn;
        }
#undef LOADSTEP
    }

    // epilogue prefetch: issue EW1/base row loads before the fold so their
    // latency hides under the shuffle reduction
    const int ej = 8 * hlane;
    const bool ep = (hlane < 8) && (ej < LD);
    const bool efull = ep && (ej < 48);
    float4 w1a, w1b, ba, bb;
    if (ep) {
        const float* e1 = EW1 + (size_t)u * LD + (efull ? ej : 48);
        w1a = *(const float4*)e1;
        if (efull) w1b = *(const float4*)(e1 + 4);
        if (base) {
            const float* bp = base + (size_t)u * LD + (efull ? ej : 48);
            ba = *(const float4*)bp;
            if (efull) bb = *(const float4*)(bp + 4);
        }
    }

    // fold within each 32-lane half: acc over 4 edge-groups; asum over 32
    float acc[8];
    #pragma unroll
    for (int k = 0; k < 4; k++) { acc[2 * k] = acc2[k].x; acc[2 * k + 1] = acc2[k].y; }
    #pragma unroll
    for (int off = 16; off >= 8; off >>= 1) {
        #pragma unroll
        for (int k = 0; k < 8; k++) acc[k] += __shfl_down(acc[k], off, 32);
        asum += __shfl_down(asum, off, 32);
    }
    asum += __shfl_xor(asum, 4);
    asum += __shfl_xor(asum, 2);
    asum += __shfl_xor(asum, 1);

    if (hlane >= 8) return;            // lanes 0..7 of each half hold cols
    const int j0 = 8 * hlane;
    if (j0 >= LD) return;              // hlane 7 -> cols 56.. out of range

    if (asum > 0.f) {
        float inv = 1.f / asum;
        if (j0 < 48) {
            acc[0] = w1a.x + acc[0] * inv; acc[1] = w1a.y + acc[1] * inv;
            acc[2] = w1a.z + acc[2] * inv; acc[3] = w1a.w + acc[3] * inv;
            acc[4] = w1b.x + acc[4] * inv; acc[5] = w1b.y + acc[5] * inv;
            acc[6] = w1b.z + acc[6] * inv; acc[7] = w1b.w + acc[7] * inv;
        } else {  // j0 == 48: cols 48,49 real; 50,51 pads (zero everywhere)
            acc[0] = w1a.x + acc[0] * inv; acc[1] = w1a.y + acc[1] * inv;
            acc[2] = w1a.z + acc[2] * inv; acc[3] = w1a.w + acc[3] * inv;
        }
    }  // else: empty segment -> 0, matching ref
    if (base) {
        if (j0 < 48) {
            acc[0] += ba.x; acc[1] += ba.y; acc[2] += ba.z; acc[3] += ba.w;
            acc[4] += bb.x; acc[5] += bb.y; acc[6] += bb.z; acc[7] += bb.w;
        } else {
            acc[0] += ba.x; acc[1] += ba.y; acc[2] += ba.z; acc[3] += ba.w;
        }
    }
    if (full_ld) {                      // stride LD=52, 16B-aligned
        if (j0 < 48) {
            *(float4*)(outp + (size_t)u * LD + j0) =
                make_float4(acc[0], acc[1], acc[2], acc[3]);
            *(float4*)(outp + (size_t)u * LD + j0 + 4) =
                make_float4(acc[4], acc[5], acc[6], acc[7]);
        } else {                        // cols 48..51 (50,51 are exact zeros)
            *(float4*)(outp + (size_t)u * LD + 48) =
                make_float4(acc[0], acc[1], acc[2], acc[3]);
        }
    } else {                            // stride DD=50, rows only 8B-aligned
        float* row = outp + (size_t)u * DD;
        if (j0 < 48) {
            *(float2*)(row + j0)     = make_float2(acc[0], acc[1]);
            *(float2*)(row + j0 + 2) = make_float2(acc[2], acc[3]);
            *(float2*)(row + j0 + 4) = make_float2(acc[4], acc[5]);
            *(float2*)(row + j0 + 6) = make_float2(acc[6], acc[7]);
        } else {
            *(float2*)(row + 48) = make_float2(acc[0], acc[1]);
        }
    }
}

// ---------------------------------------------------------------------------
extern "C" void kernel_launch(void* const* d_in, const int* in_sizes, int n_in,
                              void* d_out, int out_size, void* d_ws, size_t ws_size,
                              hipStream_t stream)
{
    const int*   h   = (const int*)d_in[0];
    const int*   r   = (const int*)d_in[1];
    const int*   t   = (const int*)d_in[2];
    const float* E   = (const float*)d_in[3];
    const float* R   = (const float*)d_in[4];
    const float* W0  = (const float*)d_in[5];
    const float* a0  = (const float*)d_in[6];
    const float* Wr0 = (const float*)d_in[7];
    const float* W1  = (const float*)d_in[8];
    const float* a1  = (const float*)d_in[9];
    const float* Wr1 = (const float*)d_in[10];
    const float* Wd  = (const float*)d_in[11];
    const float* bd  = (const float*)d_in[12];

    float* out_ent = (float*)d_out;                 // [N_ENT, DD] stride DD
    float* out_rel = out_ent + (size_t)N_ENT * DD;  // [N_REL, DD] stride DD

    // workspace layout (~92 MB)
    float* ws_f  = (float*)d_ws;
    float* EW1   = ws_f;                                   // N_ENT*LD
    float* Ed    = EW1  + (size_t)N_ENT * LD;              // N_ENT*LD
    float* e0    = Ed   + (size_t)N_ENT * LD;              // N_ENT*LD
    unsigned short* EW3h = (unsigned short*)(e0 + (size_t)N_ENT * LD);  // N_ENT*LDH bf16
    float* RW    = (float*)(EW3h + (size_t)N_ENT * LDH);   // N_REL*LD2
    float* RW1   = RW   + (size_t)N_REL * LD2;             // N_REL*LD2
    float* rel0  = RW1  + (size_t)N_REL * LD2;             // N_REL*LD
    float* sh    = rel0 + (size_t)N_REL * LD;              // N_ENT
    float* st    = sh   + N_ENT;                           // N_ENT
    float* sr    = st   + N_ENT;                           // N_REL
    float* sr1   = sr   + N_REL;                           // N_REL
    int* counts  = (int*)(sr1 + N_REL);                    // N_ENT
    int* s0      = counts + N_ENT;                         // N_ENT
    int* ccur    = s0 + N_ENT;                             // NB
    unsigned int* rtp    = (unsigned int*)(ccur + NB);     // NB*SSTRIDE (12.8 MB)
    // staging aliases the e0 region: e0 is first written by accum0, which
    // launches strictly after fse_rel1 (final_scatter) consumed the staging
    // (single stream => ordered). ent_pre0 (co-dispatched with final_scatter)
    // writes EW1/Ed/EW3h only — no overlap with e0.
    // stagedP (12.84 MB) + stagedH (6.42 MB) = 19.26 MB < e0's 20.8 MB.
    unsigned int*   stagedP = (unsigned int*)e0;                       // NB*SSTRIDE u32
    unsigned short* stagedH = (unsigned short*)(stagedP + (size_t)NB * SSTRIDE); // NB*SSTRIDE u16

    const int BLK = 256;
    const int gW  = (N_ENT / 2 + 3) / 4;         // accum: 1 wave per 2 heads

    // ---- bucket scatter || layer-0 relation precompute ----
    hipMemsetAsync(ccur, 0, (size_t)NB * sizeof(int), stream);
    bkt_rel0_kernel<<<BKT_BLOCKS + REL_BLOCKS, 512, 0, stream>>>(
        h, r, t, ccur, stagedP, stagedH, N_EDGES,
        R, Wr0, W0 + DD * DD, a0, rel0, RW, sr);

    // ---- final scatter || layer-0 entity precompute || layer-1 rel ----
    fse_rel1_kernel<<<NB + ENT_BLOCKS + REL_BLOCKS, 512, 0, stream>>>(
        stagedP, stagedH, ccur, counts, s0, rtp,
        E, W0, Wd, bd, a0, EW1, EW3h, Ed, sh, st,
        rel0, Wr1, W1 + DD * DD, a1, out_rel, RW1, sr1);

    // ---- layer 0 attention (fused score+softmax+accumulate) ----
    accum_fused_kernel<<<gW, BLK, 0, stream>>>(s0, counts, rtp, sh, sr, st,
                                               EW1, RW, EW3h, nullptr, e0, 1);

    // ---- layer 1 entity precompute ----
    ent_pre_v6<2><<<ENT_BLOCKS, 512, 0, stream>>>(e0, LD, W1, W1 + 2 * DD * DD,
                                                  nullptr, nullptr, a1,
                                                  EW1, EW3h, nullptr, sh, st);

    // ---- layer 1 attention + fused residual ----
    accum_fused_kernel<<<gW, BLK, 0, stream>>>(s0, counts, rtp, sh, sr1, st,
                                               EW1, RW1, EW3h, Ed, out_ent, 0);
}